// Round 8
// baseline (116.848 us; speedup 1.0000x reference)
//
#include <hip/hip_runtime.h>

// SpecialSpmm: out[i] = sum_{e: row_e == i} values[e] * b[col_e]
// N = 100000, E = 1600000, D = 128.
//
// Pipeline (zero global atomics):
//   K01 k01_fused:    per CH-edge chunk: LDS bucket histogram -> cnt16[c][k],
//                     PLUS grid-strided f32->bf16 cast of b (fused, hides cast)
//   K2a k2a_lofs:     wave-per-bucket prefix over chunks (cnt16 -> lofs) + totals
//   K2b k2b_scan:     one-block exclusive scan of totals -> boff
//   K3 k3_scatter:    per chunk: cur[k]=boff[k]+lofs[c][k], write records to
//                     final cv slot (LDS cursors only)
//   K4 k4_sortgather_bf16: per bucket: coalesced segment read, LDS counting
//                     sort by row, register gather of bf16 b rows
//                     (16 groups x 4 rows x bf16x8/lane), coalesced store.
//
// d_in[0] = values (E f32), d_in[1] = b (N*D f32),
// d_in[2] = indices (2*E i32: rows then cols), d_in[3] = n (1 i32).

#define D_DIM    128
#define RPB      64                    // rows per bucket
#define COLBITS  17                    // N <= 131072
#define COLMASK  ((1 << COLBITS) - 1)
#define NCMAX    512                   // max chunks supported by k2a (8/lane)
#define NBMAX    1600                  // max buckets (N <= 102400)
#define CAP      2048                  // LDS sorted capacity (records)

__device__ __forceinline__ unsigned bfr_rne(float f) {
    unsigned u = __float_as_uint(f);
    return (u + 0x7fffu + ((u >> 16) & 1u)) >> 16;
}
__device__ __forceinline__ float bf_lo(unsigned u) { return __uint_as_float(u << 16); }
__device__ __forceinline__ float bf_hi(unsigned u) { return __uint_as_float(u & 0xffff0000u); }

// ---------------- K01: per-chunk bucket histogram + fused b cast ----------------
__global__ __launch_bounds__(1024) void k01_fused(
    const int* __restrict__ idx, const float4* __restrict__ b4,
    uint4* __restrict__ bb4, unsigned short* __restrict__ cnt16,
    int E, int NBUX, int CH, int n8) {
    __shared__ int hist[NBMAX];
    int tid = threadIdx.x, c = blockIdx.x;
    int base = c * CH;
    int cnt  = min(CH, E - base);
    for (int i = tid; i < NBUX; i += 1024) hist[i] = 0;
    __syncthreads();
    for (int i = tid; i < cnt; i += 1024)
        atomicAdd(&hist[idx[base + i] >> 6], 1);
    __syncthreads();
    for (int i = tid; i < NBUX; i += 1024)
        cnt16[(size_t)c * NBUX + i] = (unsigned short)hist[i];

    // fused cast: whole-grid stride over b (independent of histogram)
    int gstride = gridDim.x * 1024;
    for (int i = blockIdx.x * 1024 + tid; i < n8; i += gstride) {
        float4 a = b4[2 * i];
        float4 d = b4[2 * i + 1];
        uint4 o;
        o.x = bfr_rne(a.x) | (bfr_rne(a.y) << 16);
        o.y = bfr_rne(a.z) | (bfr_rne(a.w) << 16);
        o.z = bfr_rne(d.x) | (bfr_rne(d.y) << 16);
        o.w = bfr_rne(d.z) | (bfr_rne(d.w) << 16);
        bb4[i] = o;
    }
}

// ---------------- K2a: wave-per-bucket prefix over chunks (<=512) ----------------
__global__ __launch_bounds__(256) void k2a_lofs(
    unsigned short* __restrict__ cnt16, int* __restrict__ total,
    int NCHUNK, int NBUX) {
    int k    = blockIdx.x * 4 + (threadIdx.x >> 6);
    int lane = threadIdx.x & 63;
    if (k >= NBUX) return;
    int PC = (NCHUNK + 63) >> 6;       // chunks per lane, <= 8
    int c0 = lane * PC;
    int vals[8];
    int sum = 0;
#pragma unroll
    for (int j = 0; j < 8; ++j) {
        int c = c0 + j;
        vals[j] = (j < PC && c < NCHUNK) ? (int)cnt16[(size_t)c * NBUX + k] : 0;
        sum += vals[j];
    }
    int v = sum;
#pragma unroll
    for (int d = 1; d < 64; d <<= 1) {
        int t = __shfl_up(v, d, 64);
        if (lane >= d) v += t;
    }
    int run = v - sum;                 // exclusive prefix for this lane's chunks
#pragma unroll
    for (int j = 0; j < 8; ++j) {
        int c = c0 + j;
        if (j < PC && c < NCHUNK) {
            cnt16[(size_t)c * NBUX + k] = (unsigned short)run;
            run += vals[j];
        }
    }
    if (lane == 63) total[k] = run;
}

// ---------------- K2b: one-block exclusive scan (n <= 2048) ----------------
__global__ void k2b_scan(const int* __restrict__ total, int* __restrict__ boff, int n) {
    __shared__ int s[256];
    int t = threadIdx.x;
    int loc[8]; int tot = 0;
#pragma unroll
    for (int j = 0; j < 8; ++j) { int i = t * 8 + j; loc[j] = (i < n) ? total[i] : 0; tot += loc[j]; }
    s[t] = tot; __syncthreads();
    for (int ofs = 1; ofs < 256; ofs <<= 1) {
        int v = (t >= ofs) ? s[t - ofs] : 0; __syncthreads();
        s[t] += v; __syncthreads();
    }
    int run = s[t] - tot;
#pragma unroll
    for (int j = 0; j < 8; ++j) { int i = t * 8 + j; if (i < n) boff[i] = run; run += loc[j]; }
    if (t == 255) boff[n] = s[255];
}

// ---------------- K3: direct-to-slot scatter ----------------
__global__ __launch_bounds__(1024) void k3_scatter(
    const int* __restrict__ idx, const float* __restrict__ values,
    const unsigned short* __restrict__ lofs, const int* __restrict__ boff,
    int2* __restrict__ cv, int E, int NBUX, int CH) {
    __shared__ int cur[NBMAX];
    int tid = threadIdx.x, c = blockIdx.x;
    int base = c * CH;
    int cnt  = min(CH, E - base);
    for (int i = tid; i < NBUX; i += 1024)
        cur[i] = boff[i] + (int)lofs[(size_t)c * NBUX + i];
    __syncthreads();
    for (int i = tid; i < cnt; i += 1024) {
        int   row = idx[base + i];
        int   col = idx[E + base + i];
        float v   = values[base + i];
        int pos = atomicAdd(&cur[row >> 6], 1);
        cv[pos] = make_int2(((row & (RPB - 1)) << COLBITS) | col, __float_as_int(v));
    }
}

// ---------------- K4: per-bucket row-sort + bf16 register gather ----------------
// 16 groups of 16 lanes; group g owns rows g*4..g*4+3; lane covers 8 of 128 dims.
__global__ __launch_bounds__(256, 8) void k4_sortgather_bf16(
    const unsigned short* __restrict__ bb, const int2* __restrict__ cv,
    const int* __restrict__ boff, float* __restrict__ out, int N) {
    __shared__ int2 sorted[CAP];                 // 16 KB
    __shared__ int  rcnt[RPB], roff[RPB], rcur[RPB];

    int tid  = threadIdx.x;
    int lane = tid & 15;
    int grp  = tid >> 4;                         // 16 groups
    int k    = blockIdx.x;
    int s    = boff[k];
    int cnt  = min(boff[k + 1] - s, CAP);

    if (tid < RPB) rcnt[tid] = 0;
    __syncthreads();

    // pass A: row histogram, coalesced segment read
    for (int i = tid; i < cnt; i += 256)
        atomicAdd(&rcnt[cv[s + i].x >> COLBITS], 1);
    __syncthreads();

    // wave-scan 64 row counts
    if (tid < 64) {
        int cval = rcnt[tid];
        int v = cval;
#pragma unroll
        for (int d = 1; d < 64; d <<= 1) {
            int t = __shfl_up(v, d, 64);
            if (tid >= d) v += t;
        }
        roff[tid] = v - cval;
        rcur[tid] = v - cval;
    }
    __syncthreads();

    // pass B: counting-scatter into sorted[] (L2-hot re-read)
    for (int i = tid; i < cnt; i += 256) {
        int2 p = cv[s + i];
        int pos = atomicAdd(&rcur[p.x >> COLBITS], 1);
        sorted[pos] = p;
    }
    __syncthreads();

    float acc[4][8];
#pragma unroll
    for (int r = 0; r < 4; ++r)
#pragma unroll
        for (int j = 0; j < 8; ++j) acc[r][j] = 0.f;

    const unsigned short* bl = bb + (lane << 3);   // lane's 8 bf16 dims

#pragma unroll
    for (int r = 0; r < 4; ++r) {
        int lr = (grp << 2) | r;
        int i  = roff[lr];
        int re = rcur[lr];
        for (; i + 1 < re; i += 2) {
            int2 p0 = sorted[i];
            int2 p1 = sorted[i + 1];
            float v0 = __int_as_float(p0.y);
            float v1 = __int_as_float(p1.y);
            const uint4 w0 = *reinterpret_cast<const uint4*>(bl + ((size_t)(p0.x & COLMASK) << 7));
            const uint4 w1 = *reinterpret_cast<const uint4*>(bl + ((size_t)(p1.x & COLMASK) << 7));
            acc[r][0] += v0 * bf_lo(w0.x); acc[r][1] += v0 * bf_hi(w0.x);
            acc[r][2] += v0 * bf_lo(w0.y); acc[r][3] += v0 * bf_hi(w0.y);
            acc[r][4] += v0 * bf_lo(w0.z); acc[r][5] += v0 * bf_hi(w0.z);
            acc[r][6] += v0 * bf_lo(w0.w); acc[r][7] += v0 * bf_hi(w0.w);
            acc[r][0] += v1 * bf_lo(w1.x); acc[r][1] += v1 * bf_hi(w1.x);
            acc[r][2] += v1 * bf_lo(w1.y); acc[r][3] += v1 * bf_hi(w1.y);
            acc[r][4] += v1 * bf_lo(w1.z); acc[r][5] += v1 * bf_hi(w1.z);
            acc[r][6] += v1 * bf_lo(w1.w); acc[r][7] += v1 * bf_hi(w1.w);
        }
        if (i < re) {
            int2 p0 = sorted[i];
            float v0 = __int_as_float(p0.y);
            const uint4 w0 = *reinterpret_cast<const uint4*>(bl + ((size_t)(p0.x & COLMASK) << 7));
            acc[r][0] += v0 * bf_lo(w0.x); acc[r][1] += v0 * bf_hi(w0.x);
            acc[r][2] += v0 * bf_lo(w0.y); acc[r][3] += v0 * bf_hi(w0.y);
            acc[r][4] += v0 * bf_lo(w0.z); acc[r][5] += v0 * bf_hi(w0.z);
            acc[r][6] += v0 * bf_lo(w0.w); acc[r][7] += v0 * bf_hi(w0.w);
        }
    }

    // coalesced store: 16 lanes x 32 B per row (also zeros empty rows)
#pragma unroll
    for (int r = 0; r < 4; ++r) {
        int row = (k << 6) + (grp << 2) + r;
        if (row < N) {
            float* po = out + ((size_t)row << 7) + (lane << 3);
            *reinterpret_cast<float4*>(po)     = make_float4(acc[r][0], acc[r][1], acc[r][2], acc[r][3]);
            *reinterpret_cast<float4*>(po + 4) = make_float4(acc[r][4], acc[r][5], acc[r][6], acc[r][7]);
        }
    }
}

// ---------------- tier-2: f32 gather ----------------
__global__ __launch_bounds__(256, 8) void k4_sortgather_f32(
    const float* __restrict__ b, const int2* __restrict__ cv,
    const int* __restrict__ boff, float* __restrict__ out, int N) {
    __shared__ int2 sorted[CAP];
    __shared__ int  rcnt[RPB], roff[RPB], rcur[RPB];
    int tid  = threadIdx.x;
    int lane = tid & 31;
    int grp  = tid >> 5;
    int k    = blockIdx.x;
    int s    = boff[k];
    int cnt  = min(boff[k + 1] - s, CAP);
    if (tid < RPB) rcnt[tid] = 0;
    __syncthreads();
    for (int i = tid; i < cnt; i += 256)
        atomicAdd(&rcnt[cv[s + i].x >> COLBITS], 1);
    __syncthreads();
    if (tid < 64) {
        int cval = rcnt[tid];
        int v = cval;
#pragma unroll
        for (int d = 1; d < 64; d <<= 1) {
            int t = __shfl_up(v, d, 64);
            if (tid >= d) v += t;
        }
        roff[tid] = v - cval;
        rcur[tid] = v - cval;
    }
    __syncthreads();
    for (int i = tid; i < cnt; i += 256) {
        int2 p = cv[s + i];
        int pos = atomicAdd(&rcur[p.x >> COLBITS], 1);
        sorted[pos] = p;
    }
    __syncthreads();
    float4 acc[8];
#pragma unroll
    for (int r = 0; r < 8; ++r) acc[r] = make_float4(0.f, 0.f, 0.f, 0.f);
    const float* bl = b + (lane << 2);
#pragma unroll
    for (int r = 0; r < 8; ++r) {
        int lr = (grp << 3) | r;
        int i  = roff[lr];
        int re = rcur[lr];
        for (; i < re; ++i) {
            int2 p0 = sorted[i];
            float v0 = __int_as_float(p0.y);
            const float4 b0 = *reinterpret_cast<const float4*>(bl + (size_t)(p0.x & COLMASK) * D_DIM);
            acc[r].x += v0 * b0.x; acc[r].y += v0 * b0.y;
            acc[r].z += v0 * b0.z; acc[r].w += v0 * b0.w;
        }
    }
#pragma unroll
    for (int r = 0; r < 8; ++r) {
        int row = (k << 6) + (grp << 3) + r;
        if (row < N)
            *reinterpret_cast<float4*>(out + (size_t)row * D_DIM + (lane << 2)) = acc[r];
    }
}

// ---------------- tier-3 fallback: atomic scatter ----------------
__global__ void spmm_atomic_scatter(const float* __restrict__ values,
                                    const float* __restrict__ b,
                                    const int* __restrict__ indices,
                                    float* __restrict__ out, int E) {
    long long gid = (long long)blockIdx.x * blockDim.x + threadIdx.x;
    long long total = (long long)E * 32;
    if (gid >= total) return;
    int e = (int)(gid >> 5);
    int c = (int)(gid & 31);
    int row = indices[e];
    int col = indices[E + e];
    float v = values[e];
    const float4 bv = *reinterpret_cast<const float4*>(b + (long long)col * D_DIM + (c << 2));
    float* o = out + (long long)row * D_DIM + (c << 2);
    atomicAdd(o + 0, v * bv.x);
    atomicAdd(o + 1, v * bv.y);
    atomicAdd(o + 2, v * bv.z);
    atomicAdd(o + 3, v * bv.w);
}

extern "C" void kernel_launch(void* const* d_in, const int* in_sizes, int n_in,
                              void* d_out, int out_size, void* d_ws, size_t ws_size,
                              hipStream_t stream) {
    const float* values = (const float*)d_in[0];
    const float* b      = (const float*)d_in[1];
    const int*   idx    = (const int*)d_in[2];
    float*       out    = (float*)d_out;

    const int E    = in_sizes[0];
    const int N    = out_size / D_DIM;
    const int NBUX = (N + RPB - 1) / RPB;

    size_t bb_bytes  = ((size_t)N * D_DIM * sizeof(unsigned short) + 15) & ~(size_t)15;
    size_t int_bytes = (((size_t)(NBUX + 1) + NBUX) * sizeof(int) + 15) & ~(size_t)15;
    size_t cv_bytes  = (size_t)E * sizeof(int2);

    // Pick chunk size: prefer 4096 (better k1/k3 occupancy); drop to 8192 if
    // the larger cnt16 table doesn't fit the workspace.
    int CH = 4096;
    int NCHUNK = (E + CH - 1) / CH;
    size_t c16_bytes = ((size_t)NCHUNK * NBUX * sizeof(unsigned short) + 15) & ~(size_t)15;
    size_t need1 = bb_bytes + int_bytes + c16_bytes + cv_bytes;
    if (ws_size < need1 || NCHUNK > NCMAX) {
        CH = 8192;
        NCHUNK = (E + CH - 1) / CH;
        c16_bytes = ((size_t)NCHUNK * NBUX * sizeof(unsigned short) + 15) & ~(size_t)15;
        need1 = bb_bytes + int_bytes + c16_bytes + cv_bytes;
    }
    size_t need2 = int_bytes + c16_bytes + cv_bytes;   // f32 tier (no bb)

    bool ok_shape = (NBUX <= NBMAX) && (NCHUNK <= NCMAX) && (N <= (1 << COLBITS));
    if (!ok_shape || ws_size < need2) {
        hipMemsetAsync(d_out, 0, (size_t)out_size * sizeof(float), stream);
        long long total = (long long)E * 32;
        int block = 256;
        long long grid = (total + block - 1) / block;
        spmm_atomic_scatter<<<(int)grid, block, 0, stream>>>(values, b, idx, out, E);
        return;
    }

    bool use_bf16 = (ws_size >= need1);
    char* base = (char*)d_ws;
    unsigned short* bb = (unsigned short*)base;
    if (use_bf16) base += bb_bytes;

    int*            boff  = (int*)base;
    int*            total = boff + (NBUX + 1);
    unsigned short* cnt16 = (unsigned short*)(base + int_bytes);
    int2*           cv    = (int2*)(base + int_bytes + c16_bytes);

    int n8 = use_bf16 ? (N * D_DIM) / 8 : 0;
    k01_fused<<<NCHUNK, 1024, 0, stream>>>(idx, (const float4*)b, (uint4*)bb,
                                           cnt16, E, NBUX, CH, n8);
    k2a_lofs<<<(NBUX + 3) / 4, 256, 0, stream>>>(cnt16, total, NCHUNK, NBUX);
    k2b_scan<<<1, 256, 0, stream>>>(total, boff, NBUX);
    k3_scatter<<<NCHUNK, 1024, 0, stream>>>(idx, values, cnt16, boff, cv, E, NBUX, CH);
    if (use_bf16)
        k4_sortgather_bf16<<<NBUX, 256, 0, stream>>>(bb, cv, boff, out, N);
    else
        k4_sortgather_f32<<<NBUX, 256, 0, stream>>>(b, cv, boff, out, N);
}

// Round 9
// 115.966 us; speedup vs baseline: 1.0076x; 1.0076x over previous
//
#include <hip/hip_runtime.h>

// SpecialSpmm: out[i] = sum_{e: row_e == i} values[e] * b[col_e]
// N = 100000, E = 1600000, D = 128.
//
// Pipeline (zero global atomics):
//   K01 k01_fused:    per CH-edge chunk: LDS bucket histogram -> cnt16[c][k],
//                     PLUS grid-strided f32->bf16 cast of b
//   K2a k2a_lofs:     wave-per-bucket prefix over chunks (cnt16 -> lofs) + totals
//   K2b k2b_scan:     one-block exclusive scan of totals -> boff
//   K3 k3_scatter:    per chunk: cur[k]=boff[k]+lofs[c][k], write records to
//                     final cv slot (LDS cursors only)
//   K4 k4_half_bf16:  TWO blocks per bucket (half = 32 rows each) for 2x grid
//                     occupancy: coalesced segment read w/ row filter, LDS
//                     counting sort, bf16 register gather (16 grp x 2 rows),
//                     coalesced store.
//
// d_in[0] = values (E f32), d_in[1] = b (N*D f32),
// d_in[2] = indices (2*E i32: rows then cols), d_in[3] = n (1 i32).

#define D_DIM    128
#define RPB      64                    // rows per bucket (sort side)
#define COLBITS  17                    // N <= 131072
#define COLMASK  ((1 << COLBITS) - 1)
#define NCMAX    512                   // max chunks supported by k2a (8/lane)
#define NBMAX    1600                  // max buckets (N <= 102400)
#define CAP      2048                  // f32-tier LDS sorted capacity
#define CAPH     1024                  // half-bucket LDS sorted capacity

__device__ __forceinline__ unsigned bfr_rne(float f) {
    unsigned u = __float_as_uint(f);
    return (u + 0x7fffu + ((u >> 16) & 1u)) >> 16;
}
__device__ __forceinline__ float bf_lo(unsigned u) { return __uint_as_float(u << 16); }
__device__ __forceinline__ float bf_hi(unsigned u) { return __uint_as_float(u & 0xffff0000u); }

// ---------------- K01: per-chunk bucket histogram + fused b cast ----------------
__global__ __launch_bounds__(1024) void k01_fused(
    const int* __restrict__ idx, const float4* __restrict__ b4,
    uint4* __restrict__ bb4, unsigned short* __restrict__ cnt16,
    int E, int NBUX, int CH, int n8) {
    __shared__ int hist[NBMAX];
    int tid = threadIdx.x, c = blockIdx.x;
    int base = c * CH;
    int cnt  = min(CH, E - base);
    for (int i = tid; i < NBUX; i += 1024) hist[i] = 0;
    __syncthreads();
    for (int i = tid; i < cnt; i += 1024)
        atomicAdd(&hist[idx[base + i] >> 6], 1);
    __syncthreads();
    for (int i = tid; i < NBUX; i += 1024)
        cnt16[(size_t)c * NBUX + i] = (unsigned short)hist[i];

    // fused cast: whole-grid stride over b (independent of histogram)
    int gstride = gridDim.x * 1024;
    for (int i = blockIdx.x * 1024 + tid; i < n8; i += gstride) {
        float4 a = b4[2 * i];
        float4 d = b4[2 * i + 1];
        uint4 o;
        o.x = bfr_rne(a.x) | (bfr_rne(a.y) << 16);
        o.y = bfr_rne(a.z) | (bfr_rne(a.w) << 16);
        o.z = bfr_rne(d.x) | (bfr_rne(d.y) << 16);
        o.w = bfr_rne(d.z) | (bfr_rne(d.w) << 16);
        bb4[i] = o;
    }
}

// ---------------- K2a: wave-per-bucket prefix over chunks (<=512) ----------------
__global__ __launch_bounds__(256) void k2a_lofs(
    unsigned short* __restrict__ cnt16, int* __restrict__ total,
    int NCHUNK, int NBUX) {
    int k    = blockIdx.x * 4 + (threadIdx.x >> 6);
    int lane = threadIdx.x & 63;
    if (k >= NBUX) return;
    int PC = (NCHUNK + 63) >> 6;       // chunks per lane, <= 8
    int c0 = lane * PC;
    int vals[8];
    int sum = 0;
#pragma unroll
    for (int j = 0; j < 8; ++j) {
        int c = c0 + j;
        vals[j] = (j < PC && c < NCHUNK) ? (int)cnt16[(size_t)c * NBUX + k] : 0;
        sum += vals[j];
    }
    int v = sum;
#pragma unroll
    for (int d = 1; d < 64; d <<= 1) {
        int t = __shfl_up(v, d, 64);
        if (lane >= d) v += t;
    }
    int run = v - sum;                 // exclusive prefix for this lane's chunks
#pragma unroll
    for (int j = 0; j < 8; ++j) {
        int c = c0 + j;
        if (j < PC && c < NCHUNK) {
            cnt16[(size_t)c * NBUX + k] = (unsigned short)run;
            run += vals[j];
        }
    }
    if (lane == 63) total[k] = run;
}

// ---------------- K2b: one-block exclusive scan (n <= 2048) ----------------
__global__ void k2b_scan(const int* __restrict__ total, int* __restrict__ boff, int n) {
    __shared__ int s[256];
    int t = threadIdx.x;
    int loc[8]; int tot = 0;
#pragma unroll
    for (int j = 0; j < 8; ++j) { int i = t * 8 + j; loc[j] = (i < n) ? total[i] : 0; tot += loc[j]; }
    s[t] = tot; __syncthreads();
    for (int ofs = 1; ofs < 256; ofs <<= 1) {
        int v = (t >= ofs) ? s[t - ofs] : 0; __syncthreads();
        s[t] += v; __syncthreads();
    }
    int run = s[t] - tot;
#pragma unroll
    for (int j = 0; j < 8; ++j) { int i = t * 8 + j; if (i < n) boff[i] = run; run += loc[j]; }
    if (t == 255) boff[n] = s[255];
}

// ---------------- K3: direct-to-slot scatter ----------------
__global__ __launch_bounds__(1024) void k3_scatter(
    const int* __restrict__ idx, const float* __restrict__ values,
    const unsigned short* __restrict__ lofs, const int* __restrict__ boff,
    int2* __restrict__ cv, int E, int NBUX, int CH) {
    __shared__ int cur[NBMAX];
    int tid = threadIdx.x, c = blockIdx.x;
    int base = c * CH;
    int cnt  = min(CH, E - base);
    for (int i = tid; i < NBUX; i += 1024)
        cur[i] = boff[i] + (int)lofs[(size_t)c * NBUX + i];
    __syncthreads();
    for (int i = tid; i < cnt; i += 1024) {
        int   row = idx[base + i];
        int   col = idx[E + base + i];
        float v   = values[base + i];
        int pos = atomicAdd(&cur[row >> 6], 1);
        cv[pos] = make_int2(((row & (RPB - 1)) << COLBITS) | col, __float_as_int(v));
    }
}

// ---------------- K4: half-bucket row-sort + bf16 register gather ----------------
// blockIdx = 2*bucket + h; handles local rows [h*32, h*32+32).
// 16 groups of 16 lanes; group g owns 2 rows; lane covers 8 of 128 dims.
__global__ __launch_bounds__(256, 8) void k4_half_bf16(
    const unsigned short* __restrict__ bb, const int2* __restrict__ cv,
    const int* __restrict__ boff, float* __restrict__ out, int N) {
    __shared__ int2 sorted[CAPH];                // 8 KB
    __shared__ int  rcnt[32], roff[32], rcur[32];

    int tid  = threadIdx.x;
    int lane = tid & 15;
    int grp  = tid >> 4;                         // 16 groups
    int k    = blockIdx.x >> 1;                  // bucket id
    int h    = blockIdx.x & 1;                   // half id (rows h*32..h*32+31)
    int s    = boff[k];
    int cnt  = boff[k + 1] - s;

    if (tid < 32) rcnt[tid] = 0;
    __syncthreads();

    // pass A: row histogram of OUR half, coalesced segment read
    for (int i = tid; i < cnt; i += 256) {
        int lrow = cv[s + i].x >> COLBITS;
        if ((lrow >> 5) == h) atomicAdd(&rcnt[lrow & 31], 1);
    }
    __syncthreads();

    // wave-scan 32 row counts
    if (tid < 32) {
        int cval = rcnt[tid];
        int v = cval;
#pragma unroll
        for (int d = 1; d < 32; d <<= 1) {
            int t = __shfl_up(v, d, 64);
            if (tid >= d) v += t;
        }
        roff[tid] = v - cval;
        rcur[tid] = v - cval;
    }
    __syncthreads();

    // pass B: counting-scatter our half into sorted[] (L2-hot re-read)
    for (int i = tid; i < cnt; i += 256) {
        int2 p = cv[s + i];
        int lrow = p.x >> COLBITS;
        if ((lrow >> 5) == h) {
            int pos = atomicAdd(&rcur[lrow & 31], 1);
            if (pos < CAPH) sorted[pos] = p;
        }
    }
    __syncthreads();

    float acc[2][8];
#pragma unroll
    for (int r = 0; r < 2; ++r)
#pragma unroll
        for (int j = 0; j < 8; ++j) acc[r][j] = 0.f;

    const unsigned short* bl = bb + (lane << 3);   // lane's 8 bf16 dims

#pragma unroll
    for (int r = 0; r < 2; ++r) {
        int lr = (grp << 1) | r;                   // 0..31 within half
        int i  = roff[lr];
        int re = min(rcur[lr], CAPH);
        for (; i + 1 < re; i += 2) {
            int2 p0 = sorted[i];
            int2 p1 = sorted[i + 1];
            float v0 = __int_as_float(p0.y);
            float v1 = __int_as_float(p1.y);
            const uint4 w0 = *reinterpret_cast<const uint4*>(bl + ((size_t)(p0.x & COLMASK) << 7));
            const uint4 w1 = *reinterpret_cast<const uint4*>(bl + ((size_t)(p1.x & COLMASK) << 7));
            acc[r][0] += v0 * bf_lo(w0.x); acc[r][1] += v0 * bf_hi(w0.x);
            acc[r][2] += v0 * bf_lo(w0.y); acc[r][3] += v0 * bf_hi(w0.y);
            acc[r][4] += v0 * bf_lo(w0.z); acc[r][5] += v0 * bf_hi(w0.z);
            acc[r][6] += v0 * bf_lo(w0.w); acc[r][7] += v0 * bf_hi(w0.w);
            acc[r][0] += v1 * bf_lo(w1.x); acc[r][1] += v1 * bf_hi(w1.x);
            acc[r][2] += v1 * bf_lo(w1.y); acc[r][3] += v1 * bf_hi(w1.y);
            acc[r][4] += v1 * bf_lo(w1.z); acc[r][5] += v1 * bf_hi(w1.z);
            acc[r][6] += v1 * bf_lo(w1.w); acc[r][7] += v1 * bf_hi(w1.w);
        }
        if (i < re) {
            int2 p0 = sorted[i];
            float v0 = __int_as_float(p0.y);
            const uint4 w0 = *reinterpret_cast<const uint4*>(bl + ((size_t)(p0.x & COLMASK) << 7));
            acc[r][0] += v0 * bf_lo(w0.x); acc[r][1] += v0 * bf_hi(w0.x);
            acc[r][2] += v0 * bf_lo(w0.y); acc[r][3] += v0 * bf_hi(w0.y);
            acc[r][4] += v0 * bf_lo(w0.z); acc[r][5] += v0 * bf_hi(w0.z);
            acc[r][6] += v0 * bf_lo(w0.w); acc[r][7] += v0 * bf_hi(w0.w);
        }
    }

    // coalesced store: 16 lanes x 32 B per row (also zeros empty rows)
#pragma unroll
    for (int r = 0; r < 2; ++r) {
        int row = (k << 6) + (h << 5) + (grp << 1) + r;
        if (row < N) {
            float* po = out + ((size_t)row << 7) + (lane << 3);
            *reinterpret_cast<float4*>(po)     = make_float4(acc[r][0], acc[r][1], acc[r][2], acc[r][3]);
            *reinterpret_cast<float4*>(po + 4) = make_float4(acc[r][4], acc[r][5], acc[r][6], acc[r][7]);
        }
    }
}

// ---------------- tier-2: f32 gather ----------------
__global__ __launch_bounds__(256, 8) void k4_sortgather_f32(
    const float* __restrict__ b, const int2* __restrict__ cv,
    const int* __restrict__ boff, float* __restrict__ out, int N) {
    __shared__ int2 sorted[CAP];
    __shared__ int  rcnt[RPB], roff[RPB], rcur[RPB];
    int tid  = threadIdx.x;
    int lane = tid & 31;
    int grp  = tid >> 5;
    int k    = blockIdx.x;
    int s    = boff[k];
    int cnt  = min(boff[k + 1] - s, CAP);
    if (tid < RPB) rcnt[tid] = 0;
    __syncthreads();
    for (int i = tid; i < cnt; i += 256)
        atomicAdd(&rcnt[cv[s + i].x >> COLBITS], 1);
    __syncthreads();
    if (tid < 64) {
        int cval = rcnt[tid];
        int v = cval;
#pragma unroll
        for (int d = 1; d < 64; d <<= 1) {
            int t = __shfl_up(v, d, 64);
            if (tid >= d) v += t;
        }
        roff[tid] = v - cval;
        rcur[tid] = v - cval;
    }
    __syncthreads();
    for (int i = tid; i < cnt; i += 256) {
        int2 p = cv[s + i];
        int pos = atomicAdd(&rcur[p.x >> COLBITS], 1);
        sorted[pos] = p;
    }
    __syncthreads();
    float4 acc[8];
#pragma unroll
    for (int r = 0; r < 8; ++r) acc[r] = make_float4(0.f, 0.f, 0.f, 0.f);
    const float* bl = b + (lane << 2);
#pragma unroll
    for (int r = 0; r < 8; ++r) {
        int lr = (grp << 3) | r;
        int i  = roff[lr];
        int re = rcur[lr];
        for (; i < re; ++i) {
            int2 p0 = sorted[i];
            float v0 = __int_as_float(p0.y);
            const float4 b0 = *reinterpret_cast<const float4*>(bl + (size_t)(p0.x & COLMASK) * D_DIM);
            acc[r].x += v0 * b0.x; acc[r].y += v0 * b0.y;
            acc[r].z += v0 * b0.z; acc[r].w += v0 * b0.w;
        }
    }
#pragma unroll
    for (int r = 0; r < 8; ++r) {
        int row = (k << 6) + (grp << 3) + r;
        if (row < N)
            *reinterpret_cast<float4*>(out + (size_t)row * D_DIM + (lane << 2)) = acc[r];
    }
}

// ---------------- tier-3 fallback: atomic scatter ----------------
__global__ void spmm_atomic_scatter(const float* __restrict__ values,
                                    const float* __restrict__ b,
                                    const int* __restrict__ indices,
                                    float* __restrict__ out, int E) {
    long long gid = (long long)blockIdx.x * blockDim.x + threadIdx.x;
    long long total = (long long)E * 32;
    if (gid >= total) return;
    int e = (int)(gid >> 5);
    int c = (int)(gid & 31);
    int row = indices[e];
    int col = indices[E + e];
    float v = values[e];
    const float4 bv = *reinterpret_cast<const float4*>(b + (long long)col * D_DIM + (c << 2));
    float* o = out + (long long)row * D_DIM + (c << 2);
    atomicAdd(o + 0, v * bv.x);
    atomicAdd(o + 1, v * bv.y);
    atomicAdd(o + 2, v * bv.z);
    atomicAdd(o + 3, v * bv.w);
}

extern "C" void kernel_launch(void* const* d_in, const int* in_sizes, int n_in,
                              void* d_out, int out_size, void* d_ws, size_t ws_size,
                              hipStream_t stream) {
    const float* values = (const float*)d_in[0];
    const float* b      = (const float*)d_in[1];
    const int*   idx    = (const int*)d_in[2];
    float*       out    = (float*)d_out;

    const int E    = in_sizes[0];
    const int N    = out_size / D_DIM;
    const int NBUX = (N + RPB - 1) / RPB;

    size_t bb_bytes  = ((size_t)N * D_DIM * sizeof(unsigned short) + 15) & ~(size_t)15;
    size_t int_bytes = (((size_t)(NBUX + 1) + NBUX) * sizeof(int) + 15) & ~(size_t)15;
    size_t cv_bytes  = (size_t)E * sizeof(int2);

    int CH = 4096;
    int NCHUNK = (E + CH - 1) / CH;
    size_t c16_bytes = ((size_t)NCHUNK * NBUX * sizeof(unsigned short) + 15) & ~(size_t)15;
    size_t need1 = bb_bytes + int_bytes + c16_bytes + cv_bytes;
    if (ws_size < need1 || NCHUNK > NCMAX) {
        CH = 8192;
        NCHUNK = (E + CH - 1) / CH;
        c16_bytes = ((size_t)NCHUNK * NBUX * sizeof(unsigned short) + 15) & ~(size_t)15;
        need1 = bb_bytes + int_bytes + c16_bytes + cv_bytes;
    }
    size_t need2 = int_bytes + c16_bytes + cv_bytes;   // f32 tier (no bb)

    bool ok_shape = (NBUX <= NBMAX) && (NCHUNK <= NCMAX) && (N <= (1 << COLBITS));
    if (!ok_shape || ws_size < need2) {
        hipMemsetAsync(d_out, 0, (size_t)out_size * sizeof(float), stream);
        long long total = (long long)E * 32;
        int block = 256;
        long long grid = (total + block - 1) / block;
        spmm_atomic_scatter<<<(int)grid, block, 0, stream>>>(values, b, idx, out, E);
        return;
    }

    bool use_bf16 = (ws_size >= need1);
    char* base = (char*)d_ws;
    unsigned short* bb = (unsigned short*)base;
    if (use_bf16) base += bb_bytes;

    int*            boff  = (int*)base;
    int*            total = boff + (NBUX + 1);
    unsigned short* cnt16 = (unsigned short*)(base + int_bytes);
    int2*           cv    = (int2*)(base + int_bytes + c16_bytes);

    int n8 = use_bf16 ? (N * D_DIM) / 8 : 0;
    k01_fused<<<NCHUNK, 1024, 0, stream>>>(idx, (const float4*)b, (uint4*)bb,
                                           cnt16, E, NBUX, CH, n8);
    k2a_lofs<<<(NBUX + 3) / 4, 256, 0, stream>>>(cnt16, total, NCHUNK, NBUX);
    k2b_scan<<<1, 256, 0, stream>>>(total, boff, NBUX);
    k3_scatter<<<NCHUNK, 1024, 0, stream>>>(idx, values, cnt16, boff, cv, E, NBUX, CH);
    if (use_bf16)
        k4_half_bf16<<<NBUX * 2, 256, 0, stream>>>(bb, cv, boff, out, N);
    else
        k4_sortgather_f32<<<NBUX, 256, 0, stream>>>(b, cv, boff, out, N);
}

// Round 10
// 114.608 us; speedup vs baseline: 1.0195x; 1.0118x over previous
//
#include <hip/hip_runtime.h>

// SpecialSpmm: out[i] = sum_{e: row_e == i} values[e] * b[col_e]
// N = 100000, E = 1600000, D = 128.
//
// Pipeline (zero global atomics):
//   K01 k01_fused:    per CH-edge chunk: LDS bucket histogram -> cnt16[c][k],
//                     PLUS grid-strided f32->bf16 cast of b
//   K2a k2a_lofs:     wave-per-bucket prefix over chunks (cnt16 -> lofs) + totals
//   K2b k2b_scan:     one-block exclusive scan of totals -> boff
//   K3 k3_scatter:    per chunk: cur[k]=boff[k]+lofs[c][k], write records to
//                     final cv slot (LDS cursors only)
//   K4 k4_reg_bf16:   per bucket: cv segment read ONCE into registers
//                     (8 rec/thread, fully unrolled), LDS hist from regs,
//                     wave-scan, reg->LDS counting scatter, then bf16 register
//                     gather (16 groups x 4 rows x bf16x8/lane), coalesced store.
//
// d_in[0] = values (E f32), d_in[1] = b (N*D f32),
// d_in[2] = indices (2*E i32: rows then cols), d_in[3] = n (1 i32).

#define D_DIM    128
#define RPB      64                    // rows per bucket
#define COLBITS  17                    // N <= 131072
#define COLMASK  ((1 << COLBITS) - 1)
#define NCMAX    512                   // max chunks supported by k2a (8/lane)
#define NBMAX    1600                  // max buckets (N <= 102400)
#define CAP      2048                  // LDS sorted capacity (records)

__device__ __forceinline__ unsigned bfr_rne(float f) {
    unsigned u = __float_as_uint(f);
    return (u + 0x7fffu + ((u >> 16) & 1u)) >> 16;
}
__device__ __forceinline__ float bf_lo(unsigned u) { return __uint_as_float(u << 16); }
__device__ __forceinline__ float bf_hi(unsigned u) { return __uint_as_float(u & 0xffff0000u); }

// ---------------- K01: per-chunk bucket histogram + fused b cast ----------------
__global__ __launch_bounds__(1024) void k01_fused(
    const int* __restrict__ idx, const float4* __restrict__ b4,
    uint4* __restrict__ bb4, unsigned short* __restrict__ cnt16,
    int E, int NBUX, int CH, int n8) {
    __shared__ int hist[NBMAX];
    int tid = threadIdx.x, c = blockIdx.x;
    int base = c * CH;
    int cnt  = min(CH, E - base);
    for (int i = tid; i < NBUX; i += 1024) hist[i] = 0;
    __syncthreads();
    for (int i = tid; i < cnt; i += 1024)
        atomicAdd(&hist[idx[base + i] >> 6], 1);
    __syncthreads();
    for (int i = tid; i < NBUX; i += 1024)
        cnt16[(size_t)c * NBUX + i] = (unsigned short)hist[i];

    // fused cast: whole-grid stride over b (independent of histogram)
    int gstride = gridDim.x * 1024;
    for (int i = blockIdx.x * 1024 + tid; i < n8; i += gstride) {
        float4 a = b4[2 * i];
        float4 d = b4[2 * i + 1];
        uint4 o;
        o.x = bfr_rne(a.x) | (bfr_rne(a.y) << 16);
        o.y = bfr_rne(a.z) | (bfr_rne(a.w) << 16);
        o.z = bfr_rne(d.x) | (bfr_rne(d.y) << 16);
        o.w = bfr_rne(d.z) | (bfr_rne(d.w) << 16);
        bb4[i] = o;
    }
}

// ---------------- K2a: wave-per-bucket prefix over chunks (<=512) ----------------
__global__ __launch_bounds__(256) void k2a_lofs(
    unsigned short* __restrict__ cnt16, int* __restrict__ total,
    int NCHUNK, int NBUX) {
    int k    = blockIdx.x * 4 + (threadIdx.x >> 6);
    int lane = threadIdx.x & 63;
    if (k >= NBUX) return;
    int PC = (NCHUNK + 63) >> 6;       // chunks per lane, <= 8
    int c0 = lane * PC;
    int vals[8];
    int sum = 0;
#pragma unroll
    for (int j = 0; j < 8; ++j) {
        int c = c0 + j;
        vals[j] = (j < PC && c < NCHUNK) ? (int)cnt16[(size_t)c * NBUX + k] : 0;
        sum += vals[j];
    }
    int v = sum;
#pragma unroll
    for (int d = 1; d < 64; d <<= 1) {
        int t = __shfl_up(v, d, 64);
        if (lane >= d) v += t;
    }
    int run = v - sum;                 // exclusive prefix for this lane's chunks
#pragma unroll
    for (int j = 0; j < 8; ++j) {
        int c = c0 + j;
        if (j < PC && c < NCHUNK) {
            cnt16[(size_t)c * NBUX + k] = (unsigned short)run;
            run += vals[j];
        }
    }
    if (lane == 63) total[k] = run;
}

// ---------------- K2b: one-block exclusive scan (n <= 2048) ----------------
__global__ void k2b_scan(const int* __restrict__ total, int* __restrict__ boff, int n) {
    __shared__ int s[256];
    int t = threadIdx.x;
    int loc[8]; int tot = 0;
#pragma unroll
    for (int j = 0; j < 8; ++j) { int i = t * 8 + j; loc[j] = (i < n) ? total[i] : 0; tot += loc[j]; }
    s[t] = tot; __syncthreads();
    for (int ofs = 1; ofs < 256; ofs <<= 1) {
        int v = (t >= ofs) ? s[t - ofs] : 0; __syncthreads();
        s[t] += v; __syncthreads();
    }
    int run = s[t] - tot;
#pragma unroll
    for (int j = 0; j < 8; ++j) { int i = t * 8 + j; if (i < n) boff[i] = run; run += loc[j]; }
    if (t == 255) boff[n] = s[255];
}

// ---------------- K3: direct-to-slot scatter ----------------
__global__ __launch_bounds__(1024) void k3_scatter(
    const int* __restrict__ idx, const float* __restrict__ values,
    const unsigned short* __restrict__ lofs, const int* __restrict__ boff,
    int2* __restrict__ cv, int E, int NBUX, int CH) {
    __shared__ int cur[NBMAX];
    int tid = threadIdx.x, c = blockIdx.x;
    int base = c * CH;
    int cnt  = min(CH, E - base);
    for (int i = tid; i < NBUX; i += 1024)
        cur[i] = boff[i] + (int)lofs[(size_t)c * NBUX + i];
    __syncthreads();
    for (int i = tid; i < cnt; i += 1024) {
        int   row = idx[base + i];
        int   col = idx[E + base + i];
        float v   = values[base + i];
        int pos = atomicAdd(&cur[row >> 6], 1);
        cv[pos] = make_int2(((row & (RPB - 1)) << COLBITS) | col, __float_as_int(v));
    }
}

// ---------------- K4: single-read reg-staged row-sort + bf16 gather ----------------
// One block per bucket. Each thread holds <=8 records in registers (static
// indexing via full unroll), LDS-histograms, scans, scatters regs->sorted[],
// then 16 groups of 16 lanes gather 4 rows each (bf16x8/lane), coalesced store.
__global__ __launch_bounds__(256, 8) void k4_reg_bf16(
    const unsigned short* __restrict__ bb, const int2* __restrict__ cv,
    const int* __restrict__ boff, float* __restrict__ out, int N) {
    __shared__ int2 sorted[CAP];                 // 16 KB
    __shared__ int  rcnt[RPB], roff[RPB], rcur[RPB];

    int tid  = threadIdx.x;
    int lane = tid & 15;
    int grp  = tid >> 4;                         // 16 groups
    int k    = blockIdx.x;
    int s    = boff[k];
    int cnt  = min(boff[k + 1] - s, CAP);

    if (tid < RPB) rcnt[tid] = 0;

    // single coalesced cv read into registers (8 rec/thread, fully unrolled)
    int2 rec[8];
#pragma unroll
    for (int j = 0; j < 8; ++j) {
        int i = tid + j * 256;
        rec[j] = (i < cnt) ? cv[s + i] : make_int2(0, 0);
    }
    __syncthreads();

    // pass A: row histogram from registers
#pragma unroll
    for (int j = 0; j < 8; ++j) {
        int i = tid + j * 256;
        if (i < cnt) atomicAdd(&rcnt[rec[j].x >> COLBITS], 1);
    }
    __syncthreads();

    // wave-scan 64 row counts
    if (tid < 64) {
        int cval = rcnt[tid];
        int v = cval;
#pragma unroll
        for (int d = 1; d < 64; d <<= 1) {
            int t = __shfl_up(v, d, 64);
            if (tid >= d) v += t;
        }
        roff[tid] = v - cval;
        rcur[tid] = v - cval;
    }
    __syncthreads();

    // pass B: counting-scatter registers -> sorted[]
#pragma unroll
    for (int j = 0; j < 8; ++j) {
        int i = tid + j * 256;
        if (i < cnt) {
            int pos = atomicAdd(&rcur[rec[j].x >> COLBITS], 1);
            sorted[pos] = rec[j];
        }
    }
    __syncthreads();

    float acc[4][8];
#pragma unroll
    for (int r = 0; r < 4; ++r)
#pragma unroll
        for (int j = 0; j < 8; ++j) acc[r][j] = 0.f;

    const unsigned short* bl = bb + (lane << 3);   // lane's 8 bf16 dims

#pragma unroll
    for (int r = 0; r < 4; ++r) {
        int lr = (grp << 2) | r;
        int i  = roff[lr];
        int re = rcur[lr];
        for (; i + 1 < re; i += 2) {
            int2 p0 = sorted[i];
            int2 p1 = sorted[i + 1];
            float v0 = __int_as_float(p0.y);
            float v1 = __int_as_float(p1.y);
            const uint4 w0 = *reinterpret_cast<const uint4*>(bl + ((size_t)(p0.x & COLMASK) << 7));
            const uint4 w1 = *reinterpret_cast<const uint4*>(bl + ((size_t)(p1.x & COLMASK) << 7));
            acc[r][0] += v0 * bf_lo(w0.x); acc[r][1] += v0 * bf_hi(w0.x);
            acc[r][2] += v0 * bf_lo(w0.y); acc[r][3] += v0 * bf_hi(w0.y);
            acc[r][4] += v0 * bf_lo(w0.z); acc[r][5] += v0 * bf_hi(w0.z);
            acc[r][6] += v0 * bf_lo(w0.w); acc[r][7] += v0 * bf_hi(w0.w);
            acc[r][0] += v1 * bf_lo(w1.x); acc[r][1] += v1 * bf_hi(w1.x);
            acc[r][2] += v1 * bf_lo(w1.y); acc[r][3] += v1 * bf_hi(w1.y);
            acc[r][4] += v1 * bf_lo(w1.z); acc[r][5] += v1 * bf_hi(w1.z);
            acc[r][6] += v1 * bf_lo(w1.w); acc[r][7] += v1 * bf_hi(w1.w);
        }
        if (i < re) {
            int2 p0 = sorted[i];
            float v0 = __int_as_float(p0.y);
            const uint4 w0 = *reinterpret_cast<const uint4*>(bl + ((size_t)(p0.x & COLMASK) << 7));
            acc[r][0] += v0 * bf_lo(w0.x); acc[r][1] += v0 * bf_hi(w0.x);
            acc[r][2] += v0 * bf_lo(w0.y); acc[r][3] += v0 * bf_hi(w0.y);
            acc[r][4] += v0 * bf_lo(w0.z); acc[r][5] += v0 * bf_hi(w0.z);
            acc[r][6] += v0 * bf_lo(w0.w); acc[r][7] += v0 * bf_hi(w0.w);
        }
    }

    // coalesced store: 16 lanes x 32 B per row (also zeros empty rows)
#pragma unroll
    for (int r = 0; r < 4; ++r) {
        int row = (k << 6) + (grp << 2) + r;
        if (row < N) {
            float* po = out + ((size_t)row << 7) + (lane << 3);
            *reinterpret_cast<float4*>(po)     = make_float4(acc[r][0], acc[r][1], acc[r][2], acc[r][3]);
            *reinterpret_cast<float4*>(po + 4) = make_float4(acc[r][4], acc[r][5], acc[r][6], acc[r][7]);
        }
    }
}

// ---------------- tier-2: f32 gather ----------------
__global__ __launch_bounds__(256, 8) void k4_sortgather_f32(
    const float* __restrict__ b, const int2* __restrict__ cv,
    const int* __restrict__ boff, float* __restrict__ out, int N) {
    __shared__ int2 sorted[CAP];
    __shared__ int  rcnt[RPB], roff[RPB], rcur[RPB];
    int tid  = threadIdx.x;
    int lane = tid & 31;
    int grp  = tid >> 5;
    int k    = blockIdx.x;
    int s    = boff[k];
    int cnt  = min(boff[k + 1] - s, CAP);
    if (tid < RPB) rcnt[tid] = 0;
    __syncthreads();
    for (int i = tid; i < cnt; i += 256)
        atomicAdd(&rcnt[cv[s + i].x >> COLBITS], 1);
    __syncthreads();
    if (tid < 64) {
        int cval = rcnt[tid];
        int v = cval;
#pragma unroll
        for (int d = 1; d < 64; d <<= 1) {
            int t = __shfl_up(v, d, 64);
            if (tid >= d) v += t;
        }
        roff[tid] = v - cval;
        rcur[tid] = v - cval;
    }
    __syncthreads();
    for (int i = tid; i < cnt; i += 256) {
        int2 p = cv[s + i];
        int pos = atomicAdd(&rcur[p.x >> COLBITS], 1);
        sorted[pos] = p;
    }
    __syncthreads();
    float4 acc[8];
#pragma unroll
    for (int r = 0; r < 8; ++r) acc[r] = make_float4(0.f, 0.f, 0.f, 0.f);
    const float* bl = b + (lane << 2);
#pragma unroll
    for (int r = 0; r < 8; ++r) {
        int lr = (grp << 3) | r;
        int i  = roff[lr];
        int re = rcur[lr];
        for (; i < re; ++i) {
            int2 p0 = sorted[i];
            float v0 = __int_as_float(p0.y);
            const float4 b0 = *reinterpret_cast<const float4*>(bl + (size_t)(p0.x & COLMASK) * D_DIM);
            acc[r].x += v0 * b0.x; acc[r].y += v0 * b0.y;
            acc[r].z += v0 * b0.z; acc[r].w += v0 * b0.w;
        }
    }
#pragma unroll
    for (int r = 0; r < 8; ++r) {
        int row = (k << 6) + (grp << 3) + r;
        if (row < N)
            *reinterpret_cast<float4*>(out + (size_t)row * D_DIM + (lane << 2)) = acc[r];
    }
}

// ---------------- tier-3 fallback: atomic scatter ----------------
__global__ void spmm_atomic_scatter(const float* __restrict__ values,
                                    const float* __restrict__ b,
                                    const int* __restrict__ indices,
                                    float* __restrict__ out, int E) {
    long long gid = (long long)blockIdx.x * blockDim.x + threadIdx.x;
    long long total = (long long)E * 32;
    if (gid >= total) return;
    int e = (int)(gid >> 5);
    int c = (int)(gid & 31);
    int row = indices[e];
    int col = indices[E + e];
    float v = values[e];
    const float4 bv = *reinterpret_cast<const float4*>(b + (long long)col * D_DIM + (c << 2));
    float* o = out + (long long)row * D_DIM + (c << 2);
    atomicAdd(o + 0, v * bv.x);
    atomicAdd(o + 1, v * bv.y);
    atomicAdd(o + 2, v * bv.z);
    atomicAdd(o + 3, v * bv.w);
}

extern "C" void kernel_launch(void* const* d_in, const int* in_sizes, int n_in,
                              void* d_out, int out_size, void* d_ws, size_t ws_size,
                              hipStream_t stream) {
    const float* values = (const float*)d_in[0];
    const float* b      = (const float*)d_in[1];
    const int*   idx    = (const int*)d_in[2];
    float*       out    = (float*)d_out;

    const int E    = in_sizes[0];
    const int N    = out_size / D_DIM;
    const int NBUX = (N + RPB - 1) / RPB;

    size_t bb_bytes  = ((size_t)N * D_DIM * sizeof(unsigned short) + 15) & ~(size_t)15;
    size_t int_bytes = (((size_t)(NBUX + 1) + NBUX) * sizeof(int) + 15) & ~(size_t)15;
    size_t cv_bytes  = (size_t)E * sizeof(int2);

    int CH = 4096;
    int NCHUNK = (E + CH - 1) / CH;
    size_t c16_bytes = ((size_t)NCHUNK * NBUX * sizeof(unsigned short) + 15) & ~(size_t)15;
    size_t need1 = bb_bytes + int_bytes + c16_bytes + cv_bytes;
    if (ws_size < need1 || NCHUNK > NCMAX) {
        CH = 8192;
        NCHUNK = (E + CH - 1) / CH;
        c16_bytes = ((size_t)NCHUNK * NBUX * sizeof(unsigned short) + 15) & ~(size_t)15;
        need1 = bb_bytes + int_bytes + c16_bytes + cv_bytes;
    }
    size_t need2 = int_bytes + c16_bytes + cv_bytes;   // f32 tier (no bb)

    bool ok_shape = (NBUX <= NBMAX) && (NCHUNK <= NCMAX) && (N <= (1 << COLBITS));
    if (!ok_shape || ws_size < need2) {
        hipMemsetAsync(d_out, 0, (size_t)out_size * sizeof(float), stream);
        long long total = (long long)E * 32;
        int block = 256;
        long long grid = (total + block - 1) / block;
        spmm_atomic_scatter<<<(int)grid, block, 0, stream>>>(values, b, idx, out, E);
        return;
    }

    bool use_bf16 = (ws_size >= need1);
    char* base = (char*)d_ws;
    unsigned short* bb = (unsigned short*)base;
    if (use_bf16) base += bb_bytes;

    int*            boff  = (int*)base;
    int*            total = boff + (NBUX + 1);
    unsigned short* cnt16 = (unsigned short*)(base + int_bytes);
    int2*           cv    = (int2*)(base + int_bytes + c16_bytes);

    int n8 = use_bf16 ? (N * D_DIM) / 8 : 0;
    k01_fused<<<NCHUNK, 1024, 0, stream>>>(idx, (const float4*)b, (uint4*)bb,
                                           cnt16, E, NBUX, CH, n8);
    k2a_lofs<<<(NBUX + 3) / 4, 256, 0, stream>>>(cnt16, total, NCHUNK, NBUX);
    k2b_scan<<<1, 256, 0, stream>>>(total, boff, NBUX);
    k3_scatter<<<NCHUNK, 1024, 0, stream>>>(idx, values, cnt16, boff, cv, E, NBUX, CH);
    if (use_bf16)
        k4_reg_bf16<<<NBUX, 256, 0, stream>>>(bb, cv, boff, out, N);
    else
        k4_sortgather_f32<<<NBUX, 256, 0, stream>>>(b, cv, boff, out, N);
}

// Round 11
// 107.411 us; speedup vs baseline: 1.0879x; 1.0670x over previous
//
#include <hip/hip_runtime.h>

// SpecialSpmm: out[i] = sum_{e: row_e == i} values[e] * b[col_e]
// N = 100000, E = 1600000, D = 128.
//
// Pipeline (zero global atomics):
//   K01 k01_fused:    per CH-edge chunk: LDS bucket histogram -> cnt16[c][k],
//                     PLUS grid-strided f32->bf16 cast of b
//   K2a k2a_lofs:     wave-per-bucket prefix over chunks (cnt16 -> lofs) + totals
//   K2b k2b_scan:     one-block exclusive scan of totals -> boff
//   K3 k3_scatter:    per chunk: cur[k]=boff[k]+lofs[c][k], write records to
//                     final cv slot. XCD-aware chunk remap: consecutive chunks
//                     (adjacent slots of every bucket region) run on the SAME
//                     XCD so cv lines fill within one L2 (no cross-XCD pingpong).
//   K4 k4_reg_bf16:   per bucket: cv segment read ONCE into registers,
//                     LDS hist from regs, wave-scan, reg->LDS counting scatter,
//                     bf16 register gather (16 grp x 4 rows x bf16x8/lane).
//
// d_in[0] = values (E f32), d_in[1] = b (N*D f32),
// d_in[2] = indices (2*E i32: rows then cols), d_in[3] = n (1 i32).

#define D_DIM    128
#define RPB      64                    // rows per bucket
#define COLBITS  17                    // N <= 131072
#define COLMASK  ((1 << COLBITS) - 1)
#define NCMAX    512                   // max chunks supported by k2a (8/lane)
#define NBMAX    1600                  // max buckets (N <= 102400)
#define CAP      2048                  // LDS sorted capacity (records)
#define NXCD     8

__device__ __forceinline__ unsigned bfr_rne(float f) {
    unsigned u = __float_as_uint(f);
    return (u + 0x7fffu + ((u >> 16) & 1u)) >> 16;
}
__device__ __forceinline__ float bf_lo(unsigned u) { return __uint_as_float(u << 16); }
__device__ __forceinline__ float bf_hi(unsigned u) { return __uint_as_float(u & 0xffff0000u); }

// Bijective XCD-chunked remap (m204): blocks on the same XCD get CONSECUTIVE
// work ids. bid%NXCD = xcd (dispatch round-robin), bid/NXCD = slot within xcd.
__device__ __forceinline__ int xcd_remap(int bid, int n) {
    int q = n / NXCD, r = n % NXCD;
    int xcd = bid % NXCD, slot = bid / NXCD;
    int base = (xcd < r) ? xcd * (q + 1) : r * (q + 1) + (xcd - r) * q;
    return base + slot;
}

// ---------------- K01: per-chunk bucket histogram + fused b cast ----------------
__global__ __launch_bounds__(1024) void k01_fused(
    const int* __restrict__ idx, const float4* __restrict__ b4,
    uint4* __restrict__ bb4, unsigned short* __restrict__ cnt16,
    int E, int NBUX, int CH, int n8) {
    __shared__ int hist[NBMAX];
    int tid = threadIdx.x, c = blockIdx.x;
    int base = c * CH;
    int cnt  = min(CH, E - base);
    for (int i = tid; i < NBUX; i += 1024) hist[i] = 0;
    __syncthreads();
    for (int i = tid; i < cnt; i += 1024)
        atomicAdd(&hist[idx[base + i] >> 6], 1);
    __syncthreads();
    for (int i = tid; i < NBUX; i += 1024)
        cnt16[(size_t)c * NBUX + i] = (unsigned short)hist[i];

    // fused cast: whole-grid stride over b (independent of histogram)
    int gstride = gridDim.x * 1024;
    for (int i = blockIdx.x * 1024 + tid; i < n8; i += gstride) {
        float4 a = b4[2 * i];
        float4 d = b4[2 * i + 1];
        uint4 o;
        o.x = bfr_rne(a.x) | (bfr_rne(a.y) << 16);
        o.y = bfr_rne(a.z) | (bfr_rne(a.w) << 16);
        o.z = bfr_rne(d.x) | (bfr_rne(d.y) << 16);
        o.w = bfr_rne(d.z) | (bfr_rne(d.w) << 16);
        bb4[i] = o;
    }
}

// ---------------- K2a: wave-per-bucket prefix over chunks (<=512) ----------------
__global__ __launch_bounds__(256) void k2a_lofs(
    unsigned short* __restrict__ cnt16, int* __restrict__ total,
    int NCHUNK, int NBUX) {
    int k    = blockIdx.x * 4 + (threadIdx.x >> 6);
    int lane = threadIdx.x & 63;
    if (k >= NBUX) return;
    int PC = (NCHUNK + 63) >> 6;       // chunks per lane, <= 8
    int c0 = lane * PC;
    int vals[8];
    int sum = 0;
#pragma unroll
    for (int j = 0; j < 8; ++j) {
        int c = c0 + j;
        vals[j] = (j < PC && c < NCHUNK) ? (int)cnt16[(size_t)c * NBUX + k] : 0;
        sum += vals[j];
    }
    int v = sum;
#pragma unroll
    for (int d = 1; d < 64; d <<= 1) {
        int t = __shfl_up(v, d, 64);
        if (lane >= d) v += t;
    }
    int run = v - sum;                 // exclusive prefix for this lane's chunks
#pragma unroll
    for (int j = 0; j < 8; ++j) {
        int c = c0 + j;
        if (j < PC && c < NCHUNK) {
            cnt16[(size_t)c * NBUX + k] = (unsigned short)run;
            run += vals[j];
        }
    }
    if (lane == 63) total[k] = run;
}

// ---------------- K2b: one-block exclusive scan (n <= 2048) ----------------
__global__ void k2b_scan(const int* __restrict__ total, int* __restrict__ boff, int n) {
    __shared__ int s[256];
    int t = threadIdx.x;
    int loc[8]; int tot = 0;
#pragma unroll
    for (int j = 0; j < 8; ++j) { int i = t * 8 + j; loc[j] = (i < n) ? total[i] : 0; tot += loc[j]; }
    s[t] = tot; __syncthreads();
    for (int ofs = 1; ofs < 256; ofs <<= 1) {
        int v = (t >= ofs) ? s[t - ofs] : 0; __syncthreads();
        s[t] += v; __syncthreads();
    }
    int run = s[t] - tot;
#pragma unroll
    for (int j = 0; j < 8; ++j) { int i = t * 8 + j; if (i < n) boff[i] = run; run += loc[j]; }
    if (t == 255) boff[n] = s[255];
}

// ---------------- K3: direct-to-slot scatter (XCD-chunked) ----------------
__global__ __launch_bounds__(1024) void k3_scatter(
    const int* __restrict__ idx, const float* __restrict__ values,
    const unsigned short* __restrict__ lofs, const int* __restrict__ boff,
    int2* __restrict__ cv, int E, int NBUX, int CH, int NCHUNK) {
    __shared__ int cur[NBMAX];
    int tid = threadIdx.x;
    int c   = xcd_remap(blockIdx.x, NCHUNK);   // same-XCD blocks -> consecutive chunks
    int base = c * CH;
    int cnt  = min(CH, E - base);
    for (int i = tid; i < NBUX; i += 1024)
        cur[i] = boff[i] + (int)lofs[(size_t)c * NBUX + i];
    __syncthreads();
    for (int i = tid; i < cnt; i += 1024) {
        int   row = idx[base + i];
        int   col = idx[E + base + i];
        float v   = values[base + i];
        int pos = atomicAdd(&cur[row >> 6], 1);
        cv[pos] = make_int2(((row & (RPB - 1)) << COLBITS) | col, __float_as_int(v));
    }
}

// ---------------- K4: single-read reg-staged row-sort + bf16 gather ----------------
__global__ __launch_bounds__(256, 8) void k4_reg_bf16(
    const unsigned short* __restrict__ bb, const int2* __restrict__ cv,
    const int* __restrict__ boff, float* __restrict__ out, int N) {
    __shared__ int2 sorted[CAP];                 // 16 KB
    __shared__ int  rcnt[RPB], roff[RPB], rcur[RPB];

    int tid  = threadIdx.x;
    int lane = tid & 15;
    int grp  = tid >> 4;                         // 16 groups
    int k    = blockIdx.x;
    int s    = boff[k];
    int cnt  = min(boff[k + 1] - s, CAP);

    if (tid < RPB) rcnt[tid] = 0;

    // single coalesced cv read into registers (8 rec/thread, fully unrolled)
    int2 rec[8];
#pragma unroll
    for (int j = 0; j < 8; ++j) {
        int i = tid + j * 256;
        rec[j] = (i < cnt) ? cv[s + i] : make_int2(0, 0);
    }
    __syncthreads();

    // pass A: row histogram from registers
#pragma unroll
    for (int j = 0; j < 8; ++j) {
        int i = tid + j * 256;
        if (i < cnt) atomicAdd(&rcnt[rec[j].x >> COLBITS], 1);
    }
    __syncthreads();

    // wave-scan 64 row counts
    if (tid < 64) {
        int cval = rcnt[tid];
        int v = cval;
#pragma unroll
        for (int d = 1; d < 64; d <<= 1) {
            int t = __shfl_up(v, d, 64);
            if (tid >= d) v += t;
        }
        roff[tid] = v - cval;
        rcur[tid] = v - cval;
    }
    __syncthreads();

    // pass B: counting-scatter registers -> sorted[]
#pragma unroll
    for (int j = 0; j < 8; ++j) {
        int i = tid + j * 256;
        if (i < cnt) {
            int pos = atomicAdd(&rcur[rec[j].x >> COLBITS], 1);
            sorted[pos] = rec[j];
        }
    }
    __syncthreads();

    float acc[4][8];
#pragma unroll
    for (int r = 0; r < 4; ++r)
#pragma unroll
        for (int j = 0; j < 8; ++j) acc[r][j] = 0.f;

    const unsigned short* bl = bb + (lane << 3);   // lane's 8 bf16 dims

#pragma unroll
    for (int r = 0; r < 4; ++r) {
        int lr = (grp << 2) | r;
        int i  = roff[lr];
        int re = rcur[lr];
        for (; i + 1 < re; i += 2) {
            int2 p0 = sorted[i];
            int2 p1 = sorted[i + 1];
            float v0 = __int_as_float(p0.y);
            float v1 = __int_as_float(p1.y);
            const uint4 w0 = *reinterpret_cast<const uint4*>(bl + ((size_t)(p0.x & COLMASK) << 7));
            const uint4 w1 = *reinterpret_cast<const uint4*>(bl + ((size_t)(p1.x & COLMASK) << 7));
            acc[r][0] += v0 * bf_lo(w0.x); acc[r][1] += v0 * bf_hi(w0.x);
            acc[r][2] += v0 * bf_lo(w0.y); acc[r][3] += v0 * bf_hi(w0.y);
            acc[r][4] += v0 * bf_lo(w0.z); acc[r][5] += v0 * bf_hi(w0.z);
            acc[r][6] += v0 * bf_lo(w0.w); acc[r][7] += v0 * bf_hi(w0.w);
            acc[r][0] += v1 * bf_lo(w1.x); acc[r][1] += v1 * bf_hi(w1.x);
            acc[r][2] += v1 * bf_lo(w1.y); acc[r][3] += v1 * bf_hi(w1.y);
            acc[r][4] += v1 * bf_lo(w1.z); acc[r][5] += v1 * bf_hi(w1.z);
            acc[r][6] += v1 * bf_lo(w1.w); acc[r][7] += v1 * bf_hi(w1.w);
        }
        if (i < re) {
            int2 p0 = sorted[i];
            float v0 = __int_as_float(p0.y);
            const uint4 w0 = *reinterpret_cast<const uint4*>(bl + ((size_t)(p0.x & COLMASK) << 7));
            acc[r][0] += v0 * bf_lo(w0.x); acc[r][1] += v0 * bf_hi(w0.x);
            acc[r][2] += v0 * bf_lo(w0.y); acc[r][3] += v0 * bf_hi(w0.y);
            acc[r][4] += v0 * bf_lo(w0.z); acc[r][5] += v0 * bf_hi(w0.z);
            acc[r][6] += v0 * bf_lo(w0.w); acc[r][7] += v0 * bf_hi(w0.w);
        }
    }

    // coalesced store: 16 lanes x 32 B per row (also zeros empty rows)
#pragma unroll
    for (int r = 0; r < 4; ++r) {
        int row = (k << 6) + (grp << 2) + r;
        if (row < N) {
            float* po = out + ((size_t)row << 7) + (lane << 3);
            *reinterpret_cast<float4*>(po)     = make_float4(acc[r][0], acc[r][1], acc[r][2], acc[r][3]);
            *reinterpret_cast<float4*>(po + 4) = make_float4(acc[r][4], acc[r][5], acc[r][6], acc[r][7]);
        }
    }
}

// ---------------- tier-2: f32 gather ----------------
__global__ __launch_bounds__(256, 8) void k4_sortgather_f32(
    const float* __restrict__ b, const int2* __restrict__ cv,
    const int* __restrict__ boff, float* __restrict__ out, int N) {
    __shared__ int2 sorted[CAP];
    __shared__ int  rcnt[RPB], roff[RPB], rcur[RPB];
    int tid  = threadIdx.x;
    int lane = tid & 31;
    int grp  = tid >> 5;
    int k    = blockIdx.x;
    int s    = boff[k];
    int cnt  = min(boff[k + 1] - s, CAP);
    if (tid < RPB) rcnt[tid] = 0;
    __syncthreads();
    for (int i = tid; i < cnt; i += 256)
        atomicAdd(&rcnt[cv[s + i].x >> COLBITS], 1);
    __syncthreads();
    if (tid < 64) {
        int cval = rcnt[tid];
        int v = cval;
#pragma unroll
        for (int d = 1; d < 64; d <<= 1) {
            int t = __shfl_up(v, d, 64);
            if (tid >= d) v += t;
        }
        roff[tid] = v - cval;
        rcur[tid] = v - cval;
    }
    __syncthreads();
    for (int i = tid; i < cnt; i += 256) {
        int2 p = cv[s + i];
        int pos = atomicAdd(&rcur[p.x >> COLBITS], 1);
        sorted[pos] = p;
    }
    __syncthreads();
    float4 acc[8];
#pragma unroll
    for (int r = 0; r < 8; ++r) acc[r] = make_float4(0.f, 0.f, 0.f, 0.f);
    const float* bl = b + (lane << 2);
#pragma unroll
    for (int r = 0; r < 8; ++r) {
        int lr = (grp << 3) | r;
        int i  = roff[lr];
        int re = rcur[lr];
        for (; i < re; ++i) {
            int2 p0 = sorted[i];
            float v0 = __int_as_float(p0.y);
            const float4 b0 = *reinterpret_cast<const float4*>(bl + (size_t)(p0.x & COLMASK) * D_DIM);
            acc[r].x += v0 * b0.x; acc[r].y += v0 * b0.y;
            acc[r].z += v0 * b0.z; acc[r].w += v0 * b0.w;
        }
    }
#pragma unroll
    for (int r = 0; r < 8; ++r) {
        int row = (k << 6) + (grp << 3) + r;
        if (row < N)
            *reinterpret_cast<float4*>(out + (size_t)row * D_DIM + (lane << 2)) = acc[r];
    }
}

// ---------------- tier-3 fallback: atomic scatter ----------------
__global__ void spmm_atomic_scatter(const float* __restrict__ values,
                                    const float* __restrict__ b,
                                    const int* __restrict__ indices,
                                    float* __restrict__ out, int E) {
    long long gid = (long long)blockIdx.x * blockDim.x + threadIdx.x;
    long long total = (long long)E * 32;
    if (gid >= total) return;
    int e = (int)(gid >> 5);
    int c = (int)(gid & 31);
    int row = indices[e];
    int col = indices[E + e];
    float v = values[e];
    const float4 bv = *reinterpret_cast<const float4*>(b + (long long)col * D_DIM + (c << 2));
    float* o = out + (long long)row * D_DIM + (c << 2);
    atomicAdd(o + 0, v * bv.x);
    atomicAdd(o + 1, v * bv.y);
    atomicAdd(o + 2, v * bv.z);
    atomicAdd(o + 3, v * bv.w);
}

extern "C" void kernel_launch(void* const* d_in, const int* in_sizes, int n_in,
                              void* d_out, int out_size, void* d_ws, size_t ws_size,
                              hipStream_t stream) {
    const float* values = (const float*)d_in[0];
    const float* b      = (const float*)d_in[1];
    const int*   idx    = (const int*)d_in[2];
    float*       out    = (float*)d_out;

    const int E    = in_sizes[0];
    const int N    = out_size / D_DIM;
    const int NBUX = (N + RPB - 1) / RPB;

    size_t bb_bytes  = ((size_t)N * D_DIM * sizeof(unsigned short) + 15) & ~(size_t)15;
    size_t int_bytes = (((size_t)(NBUX + 1) + NBUX) * sizeof(int) + 15) & ~(size_t)15;
    size_t cv_bytes  = (size_t)E * sizeof(int2);

    int CH = 4096;
    int NCHUNK = (E + CH - 1) / CH;
    size_t c16_bytes = ((size_t)NCHUNK * NBUX * sizeof(unsigned short) + 15) & ~(size_t)15;
    size_t need1 = bb_bytes + int_bytes + c16_bytes + cv_bytes;
    if (ws_size < need1 || NCHUNK > NCMAX) {
        CH = 8192;
        NCHUNK = (E + CH - 1) / CH;
        c16_bytes = ((size_t)NCHUNK * NBUX * sizeof(unsigned short) + 15) & ~(size_t)15;
        need1 = bb_bytes + int_bytes + c16_bytes + cv_bytes;
    }
    size_t need2 = int_bytes + c16_bytes + cv_bytes;   // f32 tier (no bb)

    bool ok_shape = (NBUX <= NBMAX) && (NCHUNK <= NCMAX) && (N <= (1 << COLBITS));
    if (!ok_shape || ws_size < need2) {
        hipMemsetAsync(d_out, 0, (size_t)out_size * sizeof(float), stream);
        long long total = (long long)E * 32;
        int block = 256;
        long long grid = (total + block - 1) / block;
        spmm_atomic_scatter<<<(int)grid, block, 0, stream>>>(values, b, idx, out, E);
        return;
    }

    bool use_bf16 = (ws_size >= need1);
    char* base = (char*)d_ws;
    unsigned short* bb = (unsigned short*)base;
    if (use_bf16) base += bb_bytes;

    int*            boff  = (int*)base;
    int*            total = boff + (NBUX + 1);
    unsigned short* cnt16 = (unsigned short*)(base + int_bytes);
    int2*           cv    = (int2*)(base + int_bytes + c16_bytes);

    int n8 = use_bf16 ? (N * D_DIM) / 8 : 0;
    k01_fused<<<NCHUNK, 1024, 0, stream>>>(idx, (const float4*)b, (uint4*)bb,
                                           cnt16, E, NBUX, CH, n8);
    k2a_lofs<<<(NBUX + 3) / 4, 256, 0, stream>>>(cnt16, total, NCHUNK, NBUX);
    k2b_scan<<<1, 256, 0, stream>>>(total, boff, NBUX);
    k3_scatter<<<NCHUNK, 1024, 0, stream>>>(idx, values, cnt16, boff, cv, E, NBUX, CH, NCHUNK);
    if (use_bf16)
        k4_reg_bf16<<<NBUX, 256, 0, stream>>>(bb, cv, boff, out, N);
    else
        k4_sortgather_f32<<<NBUX, 256, 0, stream>>>(b, cv, boff, out, N);
}